// Round 12
// baseline (364.950 us; speedup 1.0000x reference)
//
#include <hip/hip_runtime.h>
#include <cstdint>
#include <cstddef>

// DigitCapsule dynamic routing, fp32.
// x[256,1152,8], W[1152,10,16,8], out v[256,10,16].
// Design: lane = q*16 + d. d-reductions (logits, squash) are 16-lane
// xor-butterflies via ds_swizzle. vsum trick: logits at round r =
// votes . (v0+...+v_{r-1}).
// R12: R11 (W in LDS, proven best 169.5us) with the residency cap removed:
//   - W staged in TWO 4-i halves through ONE 20KB buffer (was 40KB) ->
//     LDS now allows 8 blocks/CU; whole 1152-block grid co-resident.
//   - waves_per_eu attr dropped: VGPR already 64 (8-wave budget); the
//     (3,4) attr was the only remaining 4-wave cap.
//   - capsF: 8 chunk-groups, b-group of 8, depth 18/thread.
constexpr int Bn = 256, In = 1152, Pn = 8, Jn = 10, Dn = 16;
constexpr int CA = 8, NCH = In / CA;  // 144 chunks
constexpr int CH2 = CA / 2;           // 4 i's per staged half

template <int MASK>
__device__ __forceinline__ float swzadd(float v) {
  const int s = __builtin_amdgcn_ds_swizzle(__float_as_int(v), MASK);
  return v + __int_as_float(s);
}

// Sum over the 16 lanes of each row (lane&15 = d); every lane gets the sum.
// ds_swizzle BitMode: offset = xor<<10 | or<<5 | and(0x1F). LDS pipe,
// pure lane permute (doesn't touch LDS storage).
__device__ __forceinline__ float rowsum16(float v) {
  v = swzadd<0x041F>(v);  // xor 1
  v = swzadd<0x081F>(v);  // xor 2
  v = swzadd<0x101F>(v);  // xor 4
  v = swzadd<0x201F>(v);  // xor 8
  return v;
}

__device__ __forceinline__ float dot8(const float4 a0, const float4 a1,
                                      const float4 b0, const float4 b1) {
  float s = a0.x * b0.x;
  s = fmaf(a0.y, b0.y, s); s = fmaf(a0.z, b0.z, s); s = fmaf(a0.w, b0.w, s);
  s = fmaf(a1.x, b1.x, s); s = fmaf(a1.y, b1.y, s); s = fmaf(a1.z, b1.z, s);
  s = fmaf(a1.w, b1.w, s);
  return s;
}

// capsV: one routing round's weighted vote sum over an i-chunk, 2 b's/thread.
// thread: d = t&15, q = t>>4; b0 = blockIdx.y*32 + q, b1 = b0 + 16.
// block = (chunk, b-group of 32).
// LDS: half-chunk of W (4 i's) as 16B units, unit = ((il*Jn+j)*2+h)*16 + d
//   (d-transposed: lane d's b128 read spans 256B -> 2-way alias, free;
//    q-groups 1..3 read identical addrs -> broadcast).
// Staging a half: 1280 units / 256 threads = 5 coalesced float4 each,
//   scattered by g -> (h=g&1, d=(g>>1)&15, ij=g>>5).
// MODE 0: softmax of zero logits = 0.1 exactly -> raw vote sum * 0.1.
template <int MODE>
__global__ __launch_bounds__(256) void capsV(
    const float* __restrict__ x, const float* __restrict__ w,
    const float* __restrict__ vsumT, float* __restrict__ spart) {
  __shared__ float4 wlds[CH2 * Jn * 2 * 16];  // 20 KB
  const int t = threadIdx.x;
  const int d = t & 15, q = t >> 4;
  const int ch = blockIdx.x;
  const int b0 = blockIdx.y * 32 + q, b1 = b0 + 16;
  const int i0 = ch * CA;

  // ---- stage half 0 (i's [i0, i0+4)) ----
  {
    const float4* wg =
        reinterpret_cast<const float4*>(w + (size_t)i0 * (Jn * Dn * Pn));
    #pragma unroll
    for (int k = 0; k < 5; ++k) {
      const int g = t + k * 256;
      const int h = g & 1, dd = (g >> 1) & 15, ij = g >> 5;
      wlds[(ij * 2 + h) * 16 + dd] = wg[g];
    }
  }

  float vs0[Jn], vs1[Jn], acc0[Jn], acc1[Jn];
  #pragma unroll
  for (int j = 0; j < Jn; ++j) {
    acc0[j] = 0.f; acc1[j] = 0.f;
    if (MODE) {
      vs0[j] = vsumT[((size_t)j * Bn + b0) * Dn + d];
      vs1[j] = vsumT[((size_t)j * Bn + b1) * Dn + d];
    }
  }

  const float* xp0 = x + ((size_t)b0 * In + i0) * Pn;
  const float* xp1 = x + ((size_t)b1 * In + i0) * Pn;

  __syncthreads();  // half 0 visible

  #pragma unroll
  for (int hh = 0; hh < 2; ++hh) {
    #pragma unroll
    for (int il = 0; il < CH2; ++il) {
      const float4 xa0 = reinterpret_cast<const float4*>(xp0)[0];
      const float4 xa1 = reinterpret_cast<const float4*>(xp0)[1];
      const float4 xb0 = reinterpret_cast<const float4*>(xp1)[0];
      const float4 xb1 = reinterpret_cast<const float4*>(xp1)[1];

      float vt0[Jn], vt1[Jn];
      #pragma unroll
      for (int j = 0; j < Jn; ++j) {
        const float4* wrow = &wlds[((il * Jn + j) * 2) * 16 + d];
        const float4 w0 = wrow[0];   // h=0
        const float4 w1 = wrow[16];  // h=1
        vt0[j] = dot8(w0, w1, xa0, xa1);
        vt1[j] = dot8(w0, w1, xb0, xb1);
      }

      if (MODE) {
        float l0[Jn], l1[Jn];
        #pragma unroll
        for (int j = 0; j < Jn; ++j) {
          l0[j] = rowsum16(vt0[j] * vs0[j]);
          l1[j] = rowsum16(vt1[j] * vs1[j]);
        }
        // softmax over j; logits are O(0.1) so no max-subtraction needed.
        float sa = 0.f, sb = 0.f;
        #pragma unroll
        for (int j = 0; j < Jn; ++j) {
          l0[j] = __expf(l0[j]); sa += l0[j];
          l1[j] = __expf(l1[j]); sb += l1[j];
        }
        const float ia = __builtin_amdgcn_rcpf(sa);
        const float ib = __builtin_amdgcn_rcpf(sb);
        #pragma unroll
        for (int j = 0; j < Jn; ++j) {
          acc0[j] = fmaf(l0[j] * ia, vt0[j], acc0[j]);
          acc1[j] = fmaf(l1[j] * ib, vt1[j], acc1[j]);
        }
      } else {
        #pragma unroll
        for (int j = 0; j < Jn; ++j) { acc0[j] += vt0[j]; acc1[j] += vt1[j]; }
      }

      xp0 += Pn;
      xp1 += Pn;
    }

    if (hh == 0) {
      __syncthreads();  // all reads of half 0 done
      const float4* wg = reinterpret_cast<const float4*>(
          w + (size_t)(i0 + CH2) * (Jn * Dn * Pn));
      #pragma unroll
      for (int k = 0; k < 5; ++k) {
        const int g = t + k * 256;
        const int h = g & 1, dd = (g >> 1) & 15, ij = g >> 5;
        wlds[(ij * 2 + h) * 16 + dd] = wg[g];
      }
      __syncthreads();  // half 1 visible
    }
  }

  const float cs = MODE ? 1.f : 0.1f;
  #pragma unroll
  for (int j = 0; j < Jn; ++j) {
    spart[(((size_t)ch * Jn + j) * Bn + b0) * Dn + d] = acc0[j] * cs;
    spart[(((size_t)ch * Jn + j) * Bn + b1) * Dn + d] = acc1[j] * cs;
  }
}

// capsF: reduce 144 chunk-partials, squash. 1024 threads: 8 chunk-groups
// (cg = t>>7) each privately sum 18 chunks for an 8b x 16d slab; LDS
// combine across cg; squash norm via rowsum16 in the t<128 tail.
// block = (j, b-group of 8), grid (10, 32).
// MODE 0: vsumT = v ; MODE 1: vsumT += v ; MODE 2: out[b][j][d] = v.
template <int MODE>
__global__ __launch_bounds__(1024) void capsF(
    const float* __restrict__ spart, float* __restrict__ vsumT,
    float* __restrict__ out) {
  __shared__ float red[8][8][16];
  const int t = threadIdx.x;
  const int cg = t >> 7, r = t & 127, g = r >> 4, d = r & 15;
  const int j = blockIdx.x, b = blockIdx.y * 8 + g;

  const size_t cstride = (size_t)Jn * Bn * Dn;  // one chunk, in floats
  const size_t cstep = 8 * cstride;             // stride between my chunks
  const float* sp = spart + (((size_t)cg * Jn + j) * Bn + b) * Dn + d;
  float s0 = 0.f, s1 = 0.f;
  #pragma unroll 3
  for (int k = 0; k < NCH / 8; k += 2) {
    s0 += sp[0];
    s1 += sp[cstep];
    sp += 2 * cstep;
  }
  red[cg][g][d] = s0 + s1;
  __syncthreads();
  if (t < 128) {
    float z = 0.f;
    #pragma unroll
    for (int c = 0; c < 8; ++c) z += red[c][g][d];
    const float n2 = rowsum16(z * z);
    const float sc = n2 / (1.f + n2) / sqrtf(n2 + 1e-7f);
    const float v = z * sc;
    if (MODE == 2) {
      out[((size_t)b * Jn + j) * Dn + d] = v;
    } else if (MODE == 1) {
      vsumT[((size_t)j * Bn + b) * Dn + d] += v;
    } else {
      vsumT[((size_t)j * Bn + b) * Dn + d] = v;
    }
  }
}

extern "C" void kernel_launch(void* const* d_in, const int* in_sizes, int n_in,
                              void* d_out, int out_size, void* d_ws, size_t ws_size,
                              hipStream_t stream) {
  const float* x = (const float*)d_in[0];  // [256,1152,8]
  const float* w = (const float*)d_in[1];  // [1152,10,16,8]
  float* vsumT = (float*)d_ws;                      // [J][B][D]   0.16 MB
  float* spart = vsumT + (size_t)Jn * Bn * Dn;      // [NCH][J][B][D] 23.6 MB
  float* out = (float*)d_out;                       // [256,10,16]

  const dim3 gV(NCH, Bn / 32), gF(Jn, Bn / 8);

  capsV<0><<<gV, 256, 0, stream>>>(x, w, nullptr, spart);
  capsF<0><<<gF, 1024, 0, stream>>>(spart, vsumT, out);   // vsum = v0

  capsV<1><<<gV, 256, 0, stream>>>(x, w, vsumT, spart);   // round 1
  capsF<1><<<gF, 1024, 0, stream>>>(spart, vsumT, out);   // vsum += v1

  capsV<1><<<gV, 256, 0, stream>>>(x, w, vsumT, spart);   // round 2
  capsF<2><<<gF, 1024, 0, stream>>>(spart, vsumT, out);   // out = v2
}

// Round 13
// 298.988 us; speedup vs baseline: 1.2206x; 1.2206x over previous
//
#include <hip/hip_runtime.h>
#include <cstdint>
#include <cstddef>

// DigitCapsule dynamic routing, fp32.
// x[256,1152,8], W[1152,10,16,8], out v[256,10,16].
// Design: lane = q*16 + d. d-reductions (logits, squash) are 16-lane
// xor-butterflies via ds_swizzle. vsum trick: logits at round r =
// votes . (v0+...+v_{r-1}).
// R13 = R11 (W in LDS, attr(3,4), proven best 169.5us / capsV 43.3us)
// + split staging: W chunk staged in TWO 4-i halves through ONE 20KB
// buffer -> LDS allows 8 blocks/CU (was 4). R12 tested this WITHOUT the
// attr and the allocator ballooned to VGPR 160 (capsV 139us) - the attr,
// not the split, was the variable. This round isolates the split.
constexpr int Bn = 256, In = 1152, Pn = 8, Jn = 10, Dn = 16;
constexpr int CA = 8, NCH = In / CA;  // 144 chunks
constexpr int CH2 = CA / 2;           // 4 i's per staged half

template <int MASK>
__device__ __forceinline__ float swzadd(float v) {
  const int s = __builtin_amdgcn_ds_swizzle(__float_as_int(v), MASK);
  return v + __int_as_float(s);
}

// Sum over the 16 lanes of each row (lane&15 = d); every lane gets the sum.
// ds_swizzle BitMode: offset = xor<<10 | or<<5 | and(0x1F). LDS pipe,
// pure lane permute (doesn't touch LDS storage).
__device__ __forceinline__ float rowsum16(float v) {
  v = swzadd<0x041F>(v);  // xor 1
  v = swzadd<0x081F>(v);  // xor 2
  v = swzadd<0x101F>(v);  // xor 4
  v = swzadd<0x201F>(v);  // xor 8
  return v;
}

__device__ __forceinline__ float dot8(const float4 a0, const float4 a1,
                                      const float4 b0, const float4 b1) {
  float s = a0.x * b0.x;
  s = fmaf(a0.y, b0.y, s); s = fmaf(a0.z, b0.z, s); s = fmaf(a0.w, b0.w, s);
  s = fmaf(a1.x, b1.x, s); s = fmaf(a1.y, b1.y, s); s = fmaf(a1.z, b1.z, s);
  s = fmaf(a1.w, b1.w, s);
  return s;
}

// capsV: one routing round's weighted vote sum over an i-chunk, 2 b's/thread.
// thread: d = t&15, q = t>>4; b0 = blockIdx.y*32 + q, b1 = b0 + 16.
// block = (chunk, b-group of 32).
// LDS: half-chunk of W (4 i's) as 16B units, unit = ((il*Jn+j)*2+h)*16 + d
//   (d-transposed: lane d's b128 read spans 256B -> 2-way alias, free;
//    q-groups 1..3 read identical addrs -> broadcast).
// Staging a half: 1280 units / 256 threads = 5 coalesced float4 each,
//   scattered by g -> (h=g&1, d=(g>>1)&15, ij=g>>5).
// MODE 0: softmax of zero logits = 0.1 exactly -> raw vote sum * 0.1.
template <int MODE>
__global__ __launch_bounds__(256)
__attribute__((amdgpu_waves_per_eu(3, 4)))
void capsV(const float* __restrict__ x, const float* __restrict__ w,
           const float* __restrict__ vsumT, float* __restrict__ spart) {
  __shared__ float4 wlds[CH2 * Jn * 2 * 16];  // 20 KB
  const int t = threadIdx.x;
  const int d = t & 15, q = t >> 4;
  const int ch = blockIdx.x;
  const int b0 = blockIdx.y * 32 + q, b1 = b0 + 16;
  const int i0 = ch * CA;

  // ---- stage half 0 (i's [i0, i0+4)) ----
  {
    const float4* wg =
        reinterpret_cast<const float4*>(w + (size_t)i0 * (Jn * Dn * Pn));
    for (int k = 0; k < 5; ++k) {
      const int g = t + k * 256;
      const int h = g & 1, dd = (g >> 1) & 15, ij = g >> 5;
      wlds[(ij * 2 + h) * 16 + dd] = wg[g];
    }
  }

  float vs0[Jn], vs1[Jn], acc0[Jn], acc1[Jn];
  #pragma unroll
  for (int j = 0; j < Jn; ++j) {
    acc0[j] = 0.f; acc1[j] = 0.f;
    if (MODE) {
      vs0[j] = vsumT[((size_t)j * Bn + b0) * Dn + d];
      vs1[j] = vsumT[((size_t)j * Bn + b1) * Dn + d];
    }
  }

  const float* xp0 = x + ((size_t)b0 * In + i0) * Pn;
  const float* xp1 = x + ((size_t)b1 * In + i0) * Pn;

  __syncthreads();  // half 0 visible

  for (int seg = 0; seg < 2; ++seg) {
    for (int il = 0; il < CH2; ++il) {
      const float4 xa0 = reinterpret_cast<const float4*>(xp0)[0];
      const float4 xa1 = reinterpret_cast<const float4*>(xp0)[1];
      const float4 xb0 = reinterpret_cast<const float4*>(xp1)[0];
      const float4 xb1 = reinterpret_cast<const float4*>(xp1)[1];

      float vt0[Jn], vt1[Jn];
      #pragma unroll
      for (int j = 0; j < Jn; ++j) {
        const float4* wrow = &wlds[((il * Jn + j) * 2) * 16 + d];
        const float4 w0 = wrow[0];   // h=0
        const float4 w1 = wrow[16];  // h=1
        vt0[j] = dot8(w0, w1, xa0, xa1);
        vt1[j] = dot8(w0, w1, xb0, xb1);
      }

      if (MODE) {
        float l0[Jn], l1[Jn];
        #pragma unroll
        for (int j = 0; j < Jn; ++j) {
          l0[j] = rowsum16(vt0[j] * vs0[j]);
          l1[j] = rowsum16(vt1[j] * vs1[j]);
        }
        // softmax over j; logits are O(0.1) so no max-subtraction needed.
        float sa = 0.f, sb = 0.f;
        #pragma unroll
        for (int j = 0; j < Jn; ++j) {
          l0[j] = __expf(l0[j]); sa += l0[j];
          l1[j] = __expf(l1[j]); sb += l1[j];
        }
        const float ia = __builtin_amdgcn_rcpf(sa);
        const float ib = __builtin_amdgcn_rcpf(sb);
        #pragma unroll
        for (int j = 0; j < Jn; ++j) {
          acc0[j] = fmaf(l0[j] * ia, vt0[j], acc0[j]);
          acc1[j] = fmaf(l1[j] * ib, vt1[j], acc1[j]);
        }
      } else {
        #pragma unroll
        for (int j = 0; j < Jn; ++j) { acc0[j] += vt0[j]; acc1[j] += vt1[j]; }
      }

      xp0 += Pn;
      xp1 += Pn;
    }

    if (seg == 0) {
      __syncthreads();  // all reads of half 0 done
      const float4* wg = reinterpret_cast<const float4*>(
          w + (size_t)(i0 + CH2) * (Jn * Dn * Pn));
      for (int k = 0; k < 5; ++k) {
        const int g = t + k * 256;
        const int h = g & 1, dd = (g >> 1) & 15, ij = g >> 5;
        wlds[(ij * 2 + h) * 16 + dd] = wg[g];
      }
      __syncthreads();  // half 1 visible
    }
  }

  const float cs = MODE ? 1.f : 0.1f;
  #pragma unroll
  for (int j = 0; j < Jn; ++j) {
    spart[(((size_t)ch * Jn + j) * Bn + b0) * Dn + d] = acc0[j] * cs;
    spart[(((size_t)ch * Jn + j) * Bn + b1) * Dn + d] = acc1[j] * cs;
  }
}

// capsF: reduce 144 chunk-partials, squash. 1024 threads: 8 chunk-groups
// (cg = t>>7) each privately sum 18 chunks for an 8b x 16d slab; LDS
// combine across cg; squash norm via rowsum16 in the t<128 tail.
// block = (j, b-group of 8), grid (10, 32).
// MODE 0: vsumT = v ; MODE 1: vsumT += v ; MODE 2: out[b][j][d] = v.
template <int MODE>
__global__ __launch_bounds__(1024) void capsF(
    const float* __restrict__ spart, float* __restrict__ vsumT,
    float* __restrict__ out) {
  __shared__ float red[8][8][16];
  const int t = threadIdx.x;
  const int cg = t >> 7, r = t & 127, g = r >> 4, d = r & 15;
  const int j = blockIdx.x, b = blockIdx.y * 8 + g;

  const size_t cstride = (size_t)Jn * Bn * Dn;  // one chunk, in floats
  const size_t cstep = 8 * cstride;             // stride between my chunks
  const float* sp = spart + (((size_t)cg * Jn + j) * Bn + b) * Dn + d;
  float s0 = 0.f, s1 = 0.f;
  #pragma unroll 3
  for (int k = 0; k < NCH / 8; k += 2) {
    s0 += sp[0];
    s1 += sp[cstep];
    sp += 2 * cstep;
  }
  red[cg][g][d] = s0 + s1;
  __syncthreads();
  if (t < 128) {
    float z = 0.f;
    #pragma unroll
    for (int c = 0; c < 8; ++c) z += red[c][g][d];
    const float n2 = rowsum16(z * z);
    const float sc = n2 / (1.f + n2) / sqrtf(n2 + 1e-7f);
    const float v = z * sc;
    if (MODE == 2) {
      out[((size_t)b * Jn + j) * Dn + d] = v;
    } else if (MODE == 1) {
      vsumT[((size_t)j * Bn + b) * Dn + d] += v;
    } else {
      vsumT[((size_t)j * Bn + b) * Dn + d] = v;
    }
  }
}

extern "C" void kernel_launch(void* const* d_in, const int* in_sizes, int n_in,
                              void* d_out, int out_size, void* d_ws, size_t ws_size,
                              hipStream_t stream) {
  const float* x = (const float*)d_in[0];  // [256,1152,8]
  const float* w = (const float*)d_in[1];  // [1152,10,16,8]
  float* vsumT = (float*)d_ws;                      // [J][B][D]   0.16 MB
  float* spart = vsumT + (size_t)Jn * Bn * Dn;      // [NCH][J][B][D] 23.6 MB
  float* out = (float*)d_out;                       // [256,10,16]

  const dim3 gV(NCH, Bn / 32), gF(Jn, Bn / 8);

  capsV<0><<<gV, 256, 0, stream>>>(x, w, nullptr, spart);
  capsF<0><<<gF, 1024, 0, stream>>>(spart, vsumT, out);   // vsum = v0

  capsV<1><<<gV, 256, 0, stream>>>(x, w, vsumT, spart);   // round 1
  capsF<1><<<gF, 1024, 0, stream>>>(spart, vsumT, out);   // vsum += v1

  capsV<1><<<gV, 256, 0, stream>>>(x, w, vsumT, spart);   // round 2
  capsF<2><<<gF, 1024, 0, stream>>>(spart, vsumT, out);   // out = v2
}

// Round 14
// 169.352 us; speedup vs baseline: 2.1550x; 1.7655x over previous
//
#include <hip/hip_runtime.h>
#include <cstdint>
#include <cstddef>

// DigitCapsule dynamic routing, fp32.
// x[256,1152,8], W[1152,10,16,8], out v[256,10,16].
// Design: lane = q*16 + d. d-reductions (logits, squash) are 16-lane
// xor-butterflies via ds_swizzle. vsum trick: logits at round r =
// votes . (v0+...+v_{r-1}).
// R14 = R11 (proven best, capsV 43.3us, VGPR-64 groove: flat ii loop,
// unrolled j-loops, attr(3,4)) + x ALSO staged in LDS (8KB padded to
// 9.2KB): the inner loop now has ZERO global ops - the 4 global x loads
// per iter were the last VMEM-latency source, the exact class the backend
// refuses to hide (R3-R10 ledger). LDS 49KB -> 3 blocks/CU (was 4); trade
// accepted since the stall source is removed, not hidden.
// Split-staging is abandoned (R12: VGPR 160; R13: scratch spill).
constexpr int Bn = 256, In = 1152, Pn = 8, Jn = 10, Dn = 16;
constexpr int CA = 8, NCH = In / CA;  // 144 chunks

template <int MASK>
__device__ __forceinline__ float swzadd(float v) {
  const int s = __builtin_amdgcn_ds_swizzle(__float_as_int(v), MASK);
  return v + __int_as_float(s);
}

// Sum over the 16 lanes of each row (lane&15 = d); every lane gets the sum.
// ds_swizzle BitMode: offset = xor<<10 | or<<5 | and(0x1F). LDS pipe,
// pure lane permute (doesn't touch LDS storage).
__device__ __forceinline__ float rowsum16(float v) {
  v = swzadd<0x041F>(v);  // xor 1
  v = swzadd<0x081F>(v);  // xor 2
  v = swzadd<0x101F>(v);  // xor 4
  v = swzadd<0x201F>(v);  // xor 8
  return v;
}

__device__ __forceinline__ float dot8(const float4 a0, const float4 a1,
                                      const float4 b0, const float4 b1) {
  float s = a0.x * b0.x;
  s = fmaf(a0.y, b0.y, s); s = fmaf(a0.z, b0.z, s); s = fmaf(a0.w, b0.w, s);
  s = fmaf(a1.x, b1.x, s); s = fmaf(a1.y, b1.y, s); s = fmaf(a1.z, b1.z, s);
  s = fmaf(a1.w, b1.w, s);
  return s;
}

// capsV: one routing round's weighted vote sum over an i-chunk, 2 b's/thread.
// thread: d = t&15, q = t>>4; b0 = blockIdx.y*32 + q, b1 = b0 + 16.
// block = (chunk, b-group of 32).
// LDS W: 16B units, unit = ((ii*Jn+j)*2+h)*16 + d (d-transposed: lane d's
//   b128 read -> 2-way bank alias, free; q-groups broadcast).
// LDS x: [32 b][18 float4] (16 used + 2 pad): read addrs per wave land
//   2 addresses per bank group -> free; staging 256B-contiguous per b.
// MODE 0: softmax of zero logits = 0.1 exactly -> raw vote sum * 0.1.
template <int MODE>
__global__ __launch_bounds__(256)
__attribute__((amdgpu_waves_per_eu(3, 4)))
void capsV(const float* __restrict__ x, const float* __restrict__ w,
           const float* __restrict__ vsumT, float* __restrict__ spart) {
  __shared__ float4 wlds[CA * Jn * 2 * 16];  // 40 KB
  __shared__ float4 xlds[32 * 18];           // 9.2 KB (pad 16->18)
  const int t = threadIdx.x;
  const int d = t & 15, q = t >> 4;
  const int ch = blockIdx.x;
  const int bbase = blockIdx.y * 32;
  const int b0 = bbase + q, b1 = b0 + 16;
  const int i0 = ch * CA;

  // ---- stage W chunk (coalesced global, permuted ds_write) ----
  {
    const float4* wg =
        reinterpret_cast<const float4*>(w + (size_t)i0 * (Jn * Dn * Pn));
    for (int k = 0; k < 10; ++k) {
      const int g = t + k * 256;
      const int h = g & 1, dd = (g >> 1) & 15, ij = g >> 5;
      wlds[(ij * 2 + h) * 16 + dd] = wg[g];
    }
  }
  // ---- stage x chunk: 32 b's x 16 float4 (8 i's x 2 halves) ----
  {
    for (int k = 0; k < 2; ++k) {
      const int u = t + k * 256;
      const int bl = u >> 4, idx = u & 15;
      xlds[bl * 18 + idx] = reinterpret_cast<const float4*>(
          x + ((size_t)(bbase + bl) * In + i0) * Pn)[idx];
    }
  }

  float vs0[Jn], vs1[Jn], acc0[Jn], acc1[Jn];
  #pragma unroll
  for (int j = 0; j < Jn; ++j) {
    acc0[j] = 0.f; acc1[j] = 0.f;
    if (MODE) {
      vs0[j] = vsumT[((size_t)j * Bn + b0) * Dn + d];
      vs1[j] = vsumT[((size_t)j * Bn + b1) * Dn + d];
    }
  }

  __syncthreads();  // staged W and x visible to all waves

  for (int ii = 0; ii < CA; ++ii) {
    const float4 xa0 = xlds[q * 18 + ii * 2];
    const float4 xa1 = xlds[q * 18 + ii * 2 + 1];
    const float4 xb0 = xlds[(q + 16) * 18 + ii * 2];
    const float4 xb1 = xlds[(q + 16) * 18 + ii * 2 + 1];

    float vt0[Jn], vt1[Jn];
    #pragma unroll
    for (int j = 0; j < Jn; ++j) {
      const float4* wrow = &wlds[((ii * Jn + j) * 2) * 16 + d];
      const float4 w0 = wrow[0];   // h=0
      const float4 w1 = wrow[16];  // h=1
      vt0[j] = dot8(w0, w1, xa0, xa1);
      vt1[j] = dot8(w0, w1, xb0, xb1);
    }

    if (MODE) {
      float l0[Jn], l1[Jn];
      #pragma unroll
      for (int j = 0; j < Jn; ++j) {
        l0[j] = rowsum16(vt0[j] * vs0[j]);
        l1[j] = rowsum16(vt1[j] * vs1[j]);
      }
      // softmax over j; logits are O(0.1) so no max-subtraction needed.
      float sa = 0.f, sb = 0.f;
      #pragma unroll
      for (int j = 0; j < Jn; ++j) {
        l0[j] = __expf(l0[j]); sa += l0[j];
        l1[j] = __expf(l1[j]); sb += l1[j];
      }
      const float ia = __builtin_amdgcn_rcpf(sa);
      const float ib = __builtin_amdgcn_rcpf(sb);
      #pragma unroll
      for (int j = 0; j < Jn; ++j) {
        acc0[j] = fmaf(l0[j] * ia, vt0[j], acc0[j]);
        acc1[j] = fmaf(l1[j] * ib, vt1[j], acc1[j]);
      }
    } else {
      #pragma unroll
      for (int j = 0; j < Jn; ++j) { acc0[j] += vt0[j]; acc1[j] += vt1[j]; }
    }
  }

  const float cs = MODE ? 1.f : 0.1f;
  #pragma unroll
  for (int j = 0; j < Jn; ++j) {
    spart[(((size_t)ch * Jn + j) * Bn + b0) * Dn + d] = acc0[j] * cs;
    spart[(((size_t)ch * Jn + j) * Bn + b1) * Dn + d] = acc1[j] * cs;
  }
}

// capsF: reduce 144 chunk-partials, squash. 1024 threads: 8 chunk-groups
// (cg = t>>7) each privately sum 18 chunks for an 8b x 16d slab; LDS
// combine across cg; squash norm via rowsum16 in the t<128 tail.
// block = (j, b-group of 8), grid (10, 32).
// MODE 0: vsumT = v ; MODE 1: vsumT += v ; MODE 2: out[b][j][d] = v.
template <int MODE>
__global__ __launch_bounds__(1024) void capsF(
    const float* __restrict__ spart, float* __restrict__ vsumT,
    float* __restrict__ out) {
  __shared__ float red[8][8][16];
  const int t = threadIdx.x;
  const int cg = t >> 7, r = t & 127, g = r >> 4, d = r & 15;
  const int j = blockIdx.x, b = blockIdx.y * 8 + g;

  const size_t cstride = (size_t)Jn * Bn * Dn;  // one chunk, in floats
  const size_t cstep = 8 * cstride;             // stride between my chunks
  const float* sp = spart + (((size_t)cg * Jn + j) * Bn + b) * Dn + d;
  float s0 = 0.f, s1 = 0.f;
  #pragma unroll 3
  for (int k = 0; k < NCH / 8; k += 2) {
    s0 += sp[0];
    s1 += sp[cstep];
    sp += 2 * cstep;
  }
  red[cg][g][d] = s0 + s1;
  __syncthreads();
  if (t < 128) {
    float z = 0.f;
    #pragma unroll
    for (int c = 0; c < 8; ++c) z += red[c][g][d];
    const float n2 = rowsum16(z * z);
    const float sc = n2 / (1.f + n2) / sqrtf(n2 + 1e-7f);
    const float v = z * sc;
    if (MODE == 2) {
      out[((size_t)b * Jn + j) * Dn + d] = v;
    } else if (MODE == 1) {
      vsumT[((size_t)j * Bn + b) * Dn + d] += v;
    } else {
      vsumT[((size_t)j * Bn + b) * Dn + d] = v;
    }
  }
}

extern "C" void kernel_launch(void* const* d_in, const int* in_sizes, int n_in,
                              void* d_out, int out_size, void* d_ws, size_t ws_size,
                              hipStream_t stream) {
  const float* x = (const float*)d_in[0];  // [256,1152,8]
  const float* w = (const float*)d_in[1];  // [1152,10,16,8]
  float* vsumT = (float*)d_ws;                      // [J][B][D]   0.16 MB
  float* spart = vsumT + (size_t)Jn * Bn * Dn;      // [NCH][J][B][D] 23.6 MB
  float* out = (float*)d_out;                       // [256,10,16]

  const dim3 gV(NCH, Bn / 32), gF(Jn, Bn / 8);

  capsV<0><<<gV, 256, 0, stream>>>(x, w, nullptr, spart);
  capsF<0><<<gF, 1024, 0, stream>>>(spart, vsumT, out);   // vsum = v0

  capsV<1><<<gV, 256, 0, stream>>>(x, w, vsumT, spart);   // round 1
  capsF<1><<<gF, 1024, 0, stream>>>(spart, vsumT, out);   // vsum += v1

  capsV<1><<<gV, 256, 0, stream>>>(x, w, vsumT, spart);   // round 2
  capsF<2><<<gF, 1024, 0, stream>>>(spart, vsumT, out);   // out = v2
}

// Round 15
// 162.195 us; speedup vs baseline: 2.2501x; 1.0441x over previous
//
#include <hip/hip_runtime.h>
#include <cstdint>
#include <cstddef>

// DigitCapsule dynamic routing, fp32.
// x[256,1152,8], W[1152,10,16,8], out v[256,10,16].
// Design: lane = q*16 + d. vsum trick: logits at round r = votes.(v0+..+v_{r-1}).
// R15 = R14 (W+x in LDS, zero-VMEM inner loop, attr(3,4) groove) with the
// 16-lane d-reduction moved from ds_swizzle (LDS pipe) to DPP adds (VALU).
// R14's null result + cycle accounting showed capsV is LDS-INSTRUCTION-
// throughput-bound: 24 b128 + 80 swizzle = ~752cy/wave-iter on the per-CU
// shared LDS unit vs 723cy/wave-iter measured. The 80 swizzles (62% of the
// wall) become v_add_f32_dpp (GCNDPPCombine fuses update_dpp+add), leaving
// LDS at 288cy/wave-iter; VALU (~880cy/wave-iter/SIMD) is the new, lower wall.
// DPP rowsum16 correctness was proven on-harness in R2/R3.
constexpr int Bn = 256, In = 1152, Pn = 8, Jn = 10, Dn = 16;
constexpr int CA = 8, NCH = In / CA;  // 144 chunks

template <int CTRL>
__device__ __forceinline__ float dpp_add(float v) {
  const int s =
      __builtin_amdgcn_update_dpp(0, __float_as_int(v), CTRL, 0xf, 0xf, true);
  return v + __int_as_float(s);  // fuses to v_add_f32_dpp
}

// Sum over the 16 lanes of each row (lane&15 = d); every lane gets the sum.
// quad_perm[1,0,3,2]=0xB1 (xor1), quad_perm[2,3,0,1]=0x4E (xor2),
// row_ror:4=0x124, row_ror:8=0x128. Pure VALU - nothing on the LDS pipe.
__device__ __forceinline__ float rowsum16(float v) {
  v = dpp_add<0xB1>(v);
  v = dpp_add<0x4E>(v);
  v = dpp_add<0x124>(v);
  v = dpp_add<0x128>(v);
  return v;
}

__device__ __forceinline__ float dot8(const float4 a0, const float4 a1,
                                      const float4 b0, const float4 b1) {
  float s = a0.x * b0.x;
  s = fmaf(a0.y, b0.y, s); s = fmaf(a0.z, b0.z, s); s = fmaf(a0.w, b0.w, s);
  s = fmaf(a1.x, b1.x, s); s = fmaf(a1.y, b1.y, s); s = fmaf(a1.z, b1.z, s);
  s = fmaf(a1.w, b1.w, s);
  return s;
}

// capsV: one routing round's weighted vote sum over an i-chunk, 2 b's/thread.
// thread: d = t&15, q = t>>4; b0 = blockIdx.y*32 + q, b1 = b0 + 16.
// block = (chunk, b-group of 32).
// LDS W: 16B units, unit = ((ii*Jn+j)*2+h)*16 + d (d-transposed: lane d's
//   b128 read -> 2-way bank alias, free; q-groups broadcast).
// LDS x: [32 b][18 float4] (16 used + 2 pad).
// MODE 0: softmax of zero logits = 0.1 exactly -> raw vote sum * 0.1.
template <int MODE>
__global__ __launch_bounds__(256)
__attribute__((amdgpu_waves_per_eu(3, 4)))
void capsV(const float* __restrict__ x, const float* __restrict__ w,
           const float* __restrict__ vsumT, float* __restrict__ spart) {
  __shared__ float4 wlds[CA * Jn * 2 * 16];  // 40 KB
  __shared__ float4 xlds[32 * 18];           // 9.2 KB (pad 16->18)
  const int t = threadIdx.x;
  const int d = t & 15, q = t >> 4;
  const int ch = blockIdx.x;
  const int bbase = blockIdx.y * 32;
  const int b0 = bbase + q, b1 = b0 + 16;
  const int i0 = ch * CA;

  // ---- stage W chunk (coalesced global, permuted ds_write) ----
  {
    const float4* wg =
        reinterpret_cast<const float4*>(w + (size_t)i0 * (Jn * Dn * Pn));
    for (int k = 0; k < 10; ++k) {
      const int g = t + k * 256;
      const int h = g & 1, dd = (g >> 1) & 15, ij = g >> 5;
      wlds[(ij * 2 + h) * 16 + dd] = wg[g];
    }
  }
  // ---- stage x chunk: 32 b's x 16 float4 (8 i's x 2 halves) ----
  {
    for (int k = 0; k < 2; ++k) {
      const int u = t + k * 256;
      const int bl = u >> 4, idx = u & 15;
      xlds[bl * 18 + idx] = reinterpret_cast<const float4*>(
          x + ((size_t)(bbase + bl) * In + i0) * Pn)[idx];
    }
  }

  float vs0[Jn], vs1[Jn], acc0[Jn], acc1[Jn];
  #pragma unroll
  for (int j = 0; j < Jn; ++j) {
    acc0[j] = 0.f; acc1[j] = 0.f;
    if (MODE) {
      vs0[j] = vsumT[((size_t)j * Bn + b0) * Dn + d];
      vs1[j] = vsumT[((size_t)j * Bn + b1) * Dn + d];
    }
  }

  __syncthreads();  // staged W and x visible to all waves

  for (int ii = 0; ii < CA; ++ii) {
    const float4 xa0 = xlds[q * 18 + ii * 2];
    const float4 xa1 = xlds[q * 18 + ii * 2 + 1];
    const float4 xb0 = xlds[(q + 16) * 18 + ii * 2];
    const float4 xb1 = xlds[(q + 16) * 18 + ii * 2 + 1];

    float vt0[Jn], vt1[Jn];
    #pragma unroll
    for (int j = 0; j < Jn; ++j) {
      const float4* wrow = &wlds[((ii * Jn + j) * 2) * 16 + d];
      const float4 w0 = wrow[0];   // h=0
      const float4 w1 = wrow[16];  // h=1
      vt0[j] = dot8(w0, w1, xa0, xa1);
      vt1[j] = dot8(w0, w1, xb0, xb1);
    }

    if (MODE) {
      float l0[Jn], l1[Jn];
      #pragma unroll
      for (int j = 0; j < Jn; ++j) {
        l0[j] = rowsum16(vt0[j] * vs0[j]);
        l1[j] = rowsum16(vt1[j] * vs1[j]);
      }
      // softmax over j; logits are O(0.1) so no max-subtraction needed.
      float sa = 0.f, sb = 0.f;
      #pragma unroll
      for (int j = 0; j < Jn; ++j) {
        l0[j] = __expf(l0[j]); sa += l0[j];
        l1[j] = __expf(l1[j]); sb += l1[j];
      }
      const float ia = __builtin_amdgcn_rcpf(sa);
      const float ib = __builtin_amdgcn_rcpf(sb);
      #pragma unroll
      for (int j = 0; j < Jn; ++j) {
        acc0[j] = fmaf(l0[j] * ia, vt0[j], acc0[j]);
        acc1[j] = fmaf(l1[j] * ib, vt1[j], acc1[j]);
      }
    } else {
      #pragma unroll
      for (int j = 0; j < Jn; ++j) { acc0[j] += vt0[j]; acc1[j] += vt1[j]; }
    }
  }

  const float cs = MODE ? 1.f : 0.1f;
  #pragma unroll
  for (int j = 0; j < Jn; ++j) {
    spart[(((size_t)ch * Jn + j) * Bn + b0) * Dn + d] = acc0[j] * cs;
    spart[(((size_t)ch * Jn + j) * Bn + b1) * Dn + d] = acc1[j] * cs;
  }
}

// capsF: reduce 144 chunk-partials, squash. 1024 threads: 8 chunk-groups
// (cg = t>>7) each privately sum 18 chunks for an 8b x 16d slab; LDS
// combine across cg; squash norm via DPP rowsum16 in the t<128 tail.
// block = (j, b-group of 8), grid (10, 32).
// MODE 0: vsumT = v ; MODE 1: vsumT += v ; MODE 2: out[b][j][d] = v.
template <int MODE>
__global__ __launch_bounds__(1024) void capsF(
    const float* __restrict__ spart, float* __restrict__ vsumT,
    float* __restrict__ out) {
  __shared__ float red[8][8][16];
  const int t = threadIdx.x;
  const int cg = t >> 7, r = t & 127, g = r >> 4, d = r & 15;
  const int j = blockIdx.x, b = blockIdx.y * 8 + g;

  const size_t cstride = (size_t)Jn * Bn * Dn;  // one chunk, in floats
  const size_t cstep = 8 * cstride;             // stride between my chunks
  const float* sp = spart + (((size_t)cg * Jn + j) * Bn + b) * Dn + d;
  float s0 = 0.f, s1 = 0.f;
  #pragma unroll 3
  for (int k = 0; k < NCH / 8; k += 2) {
    s0 += sp[0];
    s1 += sp[cstep];
    sp += 2 * cstep;
  }
  red[cg][g][d] = s0 + s1;
  __syncthreads();
  if (t < 128) {
    float z = 0.f;
    #pragma unroll
    for (int c = 0; c < 8; ++c) z += red[c][g][d];
    const float n2 = rowsum16(z * z);
    const float sc = n2 / (1.f + n2) / sqrtf(n2 + 1e-7f);
    const float v = z * sc;
    if (MODE == 2) {
      out[((size_t)b * Jn + j) * Dn + d] = v;
    } else if (MODE == 1) {
      vsumT[((size_t)j * Bn + b) * Dn + d] += v;
    } else {
      vsumT[((size_t)j * Bn + b) * Dn + d] = v;
    }
  }
}

extern "C" void kernel_launch(void* const* d_in, const int* in_sizes, int n_in,
                              void* d_out, int out_size, void* d_ws, size_t ws_size,
                              hipStream_t stream) {
  const float* x = (const float*)d_in[0];  // [256,1152,8]
  const float* w = (const float*)d_in[1];  // [1152,10,16,8]
  float* vsumT = (float*)d_ws;                      // [J][B][D]   0.16 MB
  float* spart = vsumT + (size_t)Jn * Bn * Dn;      // [NCH][J][B][D] 23.6 MB
  float* out = (float*)d_out;                       // [256,10,16]

  const dim3 gV(NCH, Bn / 32), gF(Jn, Bn / 8);

  capsV<0><<<gV, 256, 0, stream>>>(x, w, nullptr, spart);
  capsF<0><<<gF, 1024, 0, stream>>>(spart, vsumT, out);   // vsum = v0

  capsV<1><<<gV, 256, 0, stream>>>(x, w, vsumT, spart);   // round 1
  capsF<1><<<gF, 1024, 0, stream>>>(spart, vsumT, out);   // vsum += v1

  capsV<1><<<gV, 256, 0, stream>>>(x, w, vsumT, spart);   // round 2
  capsF<2><<<gF, 1024, 0, stream>>>(spart, vsumT, out);   // out = v2
}